// Round 4
// baseline (174.313 us; speedup 1.0000x reference)
//
#include <hip/hip_runtime.h>
#include <hip/hip_cooperative_groups.h>
#include <math.h>

namespace cg = cooperative_groups;

// Chamfer one-sided NN distance sum. N = M = 16384, D = 3, fp32 -> scalar fp32.
//
// Single cooperative kernel, grid (ATILES=4, SLICES=128) = 512 blocks (2/CU,
// co-resident by construction: 2 KB LDS, ~100 VGPR).
//
// Phase 1 (pair): each thread owns 16 a-points as 8 <2 x float> vectors
//   (__builtin_elementwise_fma -> v_pk_fma_f32: 3 pk_fma + 2 v_min per
//   2 pairs = 2.5 VALU/pair). Block stages 128 b-points as
//   float4(-2bx,-2by,-2bz,|b|^2) in LDS; 1 ds_read_b128 per j amortized
//   over 16 a-points. Partial mins -> ws[slice][a] (no atomics).
// grid.sync()  (cooperative; ws visible device-wide after fence+sync)
// Phase 2 (reduce): first 64 blocks: min over 128 slices (coalesced),
//   d = sqrt(max(min + |a|^2, 0)), wave + block sum, one atomicAdd/block.
//   out zeroed by block 0 in phase 1 (ordered before phase 2 by grid sync).

#define BLOCK 256
#define HPT   8                   // <2 x float> pairs per thread -> 16 a-pts
#define APT   (2 * HPT)
#define SLICES 128
#define SLICE_LEN 128             // 16384 / SLICES
#define ATILES 4                  // 16384 / (BLOCK * APT)

typedef float v2f __attribute__((ext_vector_type(2)));

__global__ __launch_bounds__(BLOCK, 2)
void cd_fused_kernel(const float* __restrict__ a,
                     const float* __restrict__ b,
                     float* __restrict__ ws,
                     float* __restrict__ out,
                     int n) {
    __shared__ float4 sb[SLICE_LEN];
    __shared__ float red[BLOCK / 64];

    const int slice = blockIdx.y;
    const int base  = slice * SLICE_LEN;
    const int fb    = blockIdx.y * ATILES + blockIdx.x;   // flat block id

    // ---- Phase 1: stage transformed B slice ----
    if (threadIdx.x < SLICE_LEN) {
        const int gj = base + threadIdx.x;
        const float x = b[3 * gj + 0];
        const float y = b[3 * gj + 1];
        const float z = b[3 * gj + 2];
        const float b2 = fmaf(x, x, fmaf(y, y, z * z));
        sb[threadIdx.x] = make_float4(-2.0f * x, -2.0f * y, -2.0f * z, b2);
    }
    if (fb == 0 && threadIdx.x == 0)
        out[0] = 0.0f;            // ordered before phase-2 atomics by grid sync
    __syncthreads();

    const int a_base = blockIdx.x * (BLOCK * APT);
    v2f ax[HPT], ay[HPT], az[HPT], best[HPT];
    #pragma unroll
    for (int h = 0; h < HPT; ++h) {
        const int i0 = a_base + (2 * h + 0) * BLOCK + threadIdx.x;
        const int i1 = a_base + (2 * h + 1) * BLOCK + threadIdx.x;
        ax[h] = (v2f){a[3 * i0 + 0], a[3 * i1 + 0]};
        ay[h] = (v2f){a[3 * i0 + 1], a[3 * i1 + 1]};
        az[h] = (v2f){a[3 * i0 + 2], a[3 * i1 + 2]};
        best[h] = (v2f){3.4028235e38f, 3.4028235e38f};
    }

    #pragma unroll 2
    for (int j = 0; j < SLICE_LEN; ++j) {
        const float4 v = sb[j];               // wave-uniform broadcast
        const v2f vx = (v2f){v.x, v.x};
        const v2f vy = (v2f){v.y, v.y};
        const v2f vz = (v2f){v.z, v.z};
        const v2f vw = (v2f){v.w, v.w};
        #pragma unroll
        for (int h = 0; h < HPT; ++h) {
            v2f t = __builtin_elementwise_fma(az[h], vz, vw);   // v_pk_fma_f32
            t = __builtin_elementwise_fma(ay[h], vy, t);
            t = __builtin_elementwise_fma(ax[h], vx, t);
            best[h] = __builtin_elementwise_min(best[h], t);    // 2x v_min_f32
        }
    }

    float* wrow = ws + (size_t)slice * n;
    #pragma unroll
    for (int h = 0; h < HPT; ++h) {
        wrow[a_base + (2 * h + 0) * BLOCK + threadIdx.x] = best[h].x;
        wrow[a_base + (2 * h + 1) * BLOCK + threadIdx.x] = best[h].y;
    }

    __threadfence();
    cg::this_grid().sync();

    // ---- Phase 2: cross-slice min + sqrt + sum (first 64 blocks) ----
    const int i = fb * BLOCK + threadIdx.x;
    if (i >= n) return;           // whole blocks retire uniformly (n % BLOCK == 0)

    float m = 3.4028235e38f;
    #pragma unroll 4
    for (int s = 0; s < SLICES; ++s)
        m = fminf(m, ws[(size_t)s * n + i]);

    const float x = a[3 * i + 0];
    const float y = a[3 * i + 1];
    const float z = a[3 * i + 2];
    const float a2 = fmaf(x, x, fmaf(y, y, z * z));
    float sum = sqrtf(fmaxf(m + a2, 0.0f));

    for (int off = 32; off > 0; off >>= 1)
        sum += __shfl_down(sum, off, 64);

    const int lane = threadIdx.x & 63;
    const int wave = threadIdx.x >> 6;
    if (lane == 0) red[wave] = sum;
    __syncthreads();
    if (threadIdx.x == 0) {
        float t = 0.0f;
        for (int w = 0; w < BLOCK / 64; ++w) t += red[w];
        atomicAdd(out, t);
    }
}

extern "C" void kernel_launch(void* const* d_in, const int* in_sizes, int n_in,
                              void* d_out, int out_size, void* d_ws, size_t ws_size,
                              hipStream_t stream) {
    const float* a = (const float*)d_in[0];
    const float* b = (const float*)d_in[1];
    float* out = (float*)d_out;
    int n = in_sizes[0] / 3;      // 16384
    float* ws = (float*)d_ws;     // SLICES * n floats = 8 MB partial mins

    dim3 grid(ATILES, SLICES);    // 512 blocks, co-resident (2 per CU)
    dim3 block(BLOCK);
    void* args[] = {(void*)&a, (void*)&b, (void*)&ws, (void*)&out, (void*)&n};
    hipLaunchCooperativeKernel((const void*)cd_fused_kernel, grid, block,
                               args, 0, stream);
}

// Round 5
// 86.867 us; speedup vs baseline: 2.0067x; 2.0067x over previous
//
#include <hip/hip_runtime.h>
#include <math.h>

// Chamfer one-sided NN distance sum. N = M = 16384, D = 3, fp32 -> scalar fp32.
//
// Two kernels (R3 structure — cooperative fusion regressed in R4: the
// non-inlined grid.sync ABI call forced the register arrays to scratch).
//
// k1 pair:   grid (a_tiles=4, slices=128) = 512 blocks. Each thread owns 16
//            a-points as 8 <2 x float> vectors; __builtin_elementwise_fma
//            emits v_pk_fma_f32. j-loop unrolled x2 with
//            fminf(fminf(t0,t1),best) -> v_min3_f32.
//            Per 4 pairs (2 a x 2 j): 6 pk_fma + 2 min3 = 2.0 VALU/pair.
//            Block stages 128 b-points as float4(-2bx,-2by,-2bz,|b|^2) in
//            LDS; ds_read_b128 broadcast, issue overlaps VALU pipe.
//            Partial mins -> ws[slice][a], no atomics. Block (0,0) zeroes
//            out[0] (stream-ordered before k2's atomicAdd).
// k2 reduce: min over 128 slices (coalesced), d = sqrt(max(min+|a|^2, 0)),
//            wave + block sum, one atomicAdd per block.

#define BLOCK 256
#define HPT   8                   // <2 x float> per thread -> 16 a-points
#define APT   (2 * HPT)
#define SLICES 128
#define SLICE_LEN 128             // 16384 / SLICES
#define ATILES 4                  // 16384 / (BLOCK * APT)

typedef float v2f __attribute__((ext_vector_type(2)));

__global__ __launch_bounds__(BLOCK)
void cd_pair_kernel(const float* __restrict__ a,
                    const float* __restrict__ b,
                    float* __restrict__ ws,
                    float* __restrict__ out,
                    int n) {
    __shared__ float4 sb[SLICE_LEN];
    const int slice = blockIdx.y;
    const int base  = slice * SLICE_LEN;

    if (threadIdx.x < SLICE_LEN) {
        const int gj = base + threadIdx.x;
        const float x = b[3 * gj + 0];
        const float y = b[3 * gj + 1];
        const float z = b[3 * gj + 2];
        const float b2 = fmaf(x, x, fmaf(y, y, z * z));
        sb[threadIdx.x] = make_float4(-2.0f * x, -2.0f * y, -2.0f * z, b2);
    }
    if (blockIdx.x == 0 && blockIdx.y == 0 && threadIdx.x == 0)
        out[0] = 0.0f;            // replaces memset node; k2 ordered after k1
    __syncthreads();

    const int a_base = blockIdx.x * (BLOCK * APT);
    v2f ax[HPT], ay[HPT], az[HPT], best[HPT];
    #pragma unroll
    for (int h = 0; h < HPT; ++h) {
        const int i0 = a_base + (2 * h + 0) * BLOCK + threadIdx.x;
        const int i1 = a_base + (2 * h + 1) * BLOCK + threadIdx.x;
        ax[h] = (v2f){a[3 * i0 + 0], a[3 * i1 + 0]};
        ay[h] = (v2f){a[3 * i0 + 1], a[3 * i1 + 1]};
        az[h] = (v2f){a[3 * i0 + 2], a[3 * i1 + 2]};
        best[h] = (v2f){3.4028235e38f, 3.4028235e38f};
    }

    for (int j = 0; j < SLICE_LEN; j += 2) {
        const float4 v0 = sb[j];              // wave-uniform broadcast
        const float4 v1 = sb[j + 1];
        #pragma unroll
        for (int h = 0; h < HPT; ++h) {
            v2f t0 = __builtin_elementwise_fma(az[h], (v2f){v0.z, v0.z}, (v2f){v0.w, v0.w});
            t0 = __builtin_elementwise_fma(ay[h], (v2f){v0.y, v0.y}, t0);
            t0 = __builtin_elementwise_fma(ax[h], (v2f){v0.x, v0.x}, t0);
            v2f t1 = __builtin_elementwise_fma(az[h], (v2f){v1.z, v1.z}, (v2f){v1.w, v1.w});
            t1 = __builtin_elementwise_fma(ay[h], (v2f){v1.y, v1.y}, t1);
            t1 = __builtin_elementwise_fma(ax[h], (v2f){v1.x, v1.x}, t1);
            // min(min(t0,t1),best) folds to v_min3_f32 per component
            best[h].x = fminf(fminf(t0.x, t1.x), best[h].x);
            best[h].y = fminf(fminf(t0.y, t1.y), best[h].y);
        }
    }

    float* wrow = ws + (size_t)slice * n;
    #pragma unroll
    for (int h = 0; h < HPT; ++h) {
        wrow[a_base + (2 * h + 0) * BLOCK + threadIdx.x] = best[h].x;
        wrow[a_base + (2 * h + 1) * BLOCK + threadIdx.x] = best[h].y;
    }
}

__global__ __launch_bounds__(BLOCK)
void cd_reduce_kernel(const float* __restrict__ a,
                      const float* __restrict__ ws,
                      float* __restrict__ out,
                      int n) {
    __shared__ float red[BLOCK / 64];
    const int i = blockIdx.x * BLOCK + threadIdx.x;   // one thread per a-point

    float m = 3.4028235e38f;
    #pragma unroll 4
    for (int s = 0; s < SLICES; ++s)
        m = fminf(m, ws[(size_t)s * n + i]);          // coalesced

    const float x = a[3 * i + 0];
    const float y = a[3 * i + 1];
    const float z = a[3 * i + 2];
    const float a2 = fmaf(x, x, fmaf(y, y, z * z));
    float sum = sqrtf(fmaxf(m + a2, 0.0f));

    for (int off = 32; off > 0; off >>= 1)
        sum += __shfl_down(sum, off, 64);

    const int lane = threadIdx.x & 63;
    const int wave = threadIdx.x >> 6;
    if (lane == 0) red[wave] = sum;
    __syncthreads();
    if (threadIdx.x == 0) {
        float t = 0.0f;
        for (int w = 0; w < BLOCK / 64; ++w) t += red[w];
        atomicAdd(out, t);
    }
}

extern "C" void kernel_launch(void* const* d_in, const int* in_sizes, int n_in,
                              void* d_out, int out_size, void* d_ws, size_t ws_size,
                              hipStream_t stream) {
    const float* a = (const float*)d_in[0];
    const float* b = (const float*)d_in[1];
    float* out = (float*)d_out;
    const int n = in_sizes[0] / 3;    // 16384
    float* ws = (float*)d_ws;         // SLICES * n floats = 8 MB

    dim3 grid(ATILES, SLICES);        // 4 x 128 = 512 blocks
    cd_pair_kernel<<<grid, BLOCK, 0, stream>>>(a, b, ws, out, n);
    cd_reduce_kernel<<<n / BLOCK, BLOCK, 0, stream>>>(a, ws, out, n);
}